// Round 16
// baseline (177.197 us; speedup 1.0000x reference)
//
#include <hip/hip_runtime.h>
#include <stdint.h>

// SpatialHyperedgeMP: out = ((inc + head) @ cur) / rowsum(inc + head)
//   head_ij = (inc_ij > 0) / sqrt(cnt_i),  cnt_i = #positives in row i
//
// R16: back to SINGLE GEMM + stats prepass. Dual-GEMM rounds (R5-R15) pinned at
//   ~167us: DS demand (A+M frags x 8 waves) 25% above MFMA, and every schedule
//   remedy moved cost to a latency path. Algebra instead: prepass computes
//   invs/rdeg (R1-proven kernel, one 268MB stream ~40us); gemm stages
//   bf16(inc + mask*invs) (R3-proven numerics) -> M gone from LDS entirely:
//   DS halved (770 cyc/slot), MFMA halved (33us), VALU halved. Gemm pipes
//   balanced at ~41us ideal; x1.8 observed stall ~80us. Total ~130us.
//   Pipeline = R15's (4 A-buffers, sync per 2 tiles, B reg ping-pong,
//   nt-by-XCD-half swizzle, 512 thr, 2 blk/CU).
//
// ws: invs 32KB @0, rdeg 32KB @32768, B chunks 8MB @65536.

#define NROWS 8192
#define DDIM  512

typedef float f32x4 __attribute__((ext_vector_type(4)));
typedef short s16x8 __attribute__((ext_vector_type(8)));

__device__ __forceinline__ unsigned short f2bf(float f) {
  union { float f; unsigned int u; } c; c.f = f;
  unsigned int u = c.u;
  unsigned int r = u + 0x7FFFu + ((u >> 16) & 1u);
  return (unsigned short)(r >> 16);
}

// ---------------- kernel 1: row stats (R1-proven) ----------------
__global__ __launch_bounds__(256) void stats_kernel(const float* __restrict__ inc,
                                                    float* __restrict__ invs,
                                                    float* __restrict__ rdeg) {
  int row = blockIdx.x;
  int tid = threadIdx.x;
  const float4* p = (const float4*)(inc + (size_t)row * NROWS);
  double s = 0.0;
  int c = 0;
#pragma unroll
  for (int i = 0; i < 8; ++i) {
    float4 v = p[i * 256 + tid];
    s += (double)v.x + (double)v.y + (double)v.z + (double)v.w;
    c += (v.x > 0.f) + (v.y > 0.f) + (v.z > 0.f) + (v.w > 0.f);
  }
  for (int off = 32; off > 0; off >>= 1) {
    s += __shfl_down(s, off);
    c += __shfl_down(c, off);
  }
  __shared__ double sw[4];
  __shared__ int cw[4];
  int lane = tid & 63, wv = tid >> 6;
  if (lane == 0) { sw[wv] = s; cw[wv] = c; }
  __syncthreads();
  if (tid == 0) {
    double S = sw[0] + sw[1] + sw[2] + sw[3];
    int C = cw[0] + cw[1] + cw[2] + cw[3];
    double sq = sqrt((double)C);
    invs[row] = (C > 0) ? (float)(1.0 / sq) : 0.0f;
    rdeg[row] = (float)(1.0 / (S + sq));
  }
}

// ---------------- kernel 2: B prep (cur -> bf16 chunked-transposed) ----------------
// chunk layout: nt(2) x kt(128): 32KB chunk = [kg=8][nn=256][e=8] bf16
__global__ __launch_bounds__(256) void bprep_kernel(const float* __restrict__ cur,
                                                    unsigned char* __restrict__ bws) {
  int idx = blockIdx.x * 256 + threadIdx.x;  // 0..524287
  int n = idx & 511;
  int kg9 = idx >> 9;  // 0..1023
  int kt = kg9 >> 3;
  int kg = kg9 & 7;
  int k0 = kt * 64 + kg * 8;
  union { unsigned short h[8]; uint4 q; } u;
#pragma unroll
  for (int e = 0; e < 8; ++e)
    u.h[e] = f2bf(cur[(size_t)(k0 + e) * DDIM + n]);
  int nt = n >> 8, nn = n & 255;
  size_t off = ((size_t)(nt * 128 + kt) << 15) + ((size_t)kg << 12) + ((size_t)nn << 4);
  *(uint4*)(bws + off) = u.q;
}

// ---------------- kernel 3: single GEMM, fused head-add at staging ----------------
// BM=32 BN=256 BK=64, 512 thr = 8 waves (1M x 8N), wave tile 32x32.
// LDS (16.6KB): 4 A buffers x 4KB ([kg=8][slot=32][16B], slot=row^kg, 0-conflict)
// + rdeg[32]. Sync per 2 tiles; B frags direct ws->reg, bX/bY ping-pong.

#define FENCE() __builtin_amdgcn_sched_barrier(0)
#define BARRIER() __builtin_amdgcn_s_barrier()
#define WAITLGKM() asm volatile("s_waitcnt lgkmcnt(0)" ::: "memory")
#define MFMA_ __builtin_amdgcn_mfma_f32_16x16x32_bf16

__global__ __launch_bounds__(512, 4) void gemm_kernel(const float* __restrict__ inc,
                                                      const unsigned char* __restrict__ bws,
                                                      const float* __restrict__ invs,
                                                      const float* __restrict__ rdeg,
                                                      float* __restrict__ out) {
  __shared__ __align__(16) unsigned char smem[16512];
  unsigned char* const buf0 = smem;
  unsigned char* const buf1 = smem + 4096;
  unsigned char* const buf2 = smem + 8192;
  unsigned char* const buf3 = smem + 12288;
  float* const rdegS = (float*)(smem + 16384);  // 32 floats

  const int tid = threadIdx.x;
  const int lane = tid & 63;
  const int wv = tid >> 6;       // 0..7 column group
  const int r = lane & 15;
  const int q = lane >> 4;       // 0..3

  const int id = blockIdx.x;     // 0..511
  const int nt = (id & 7) >> 2;  // XCD half -> fixed 4MB B chunk per XCD L2
  const int mt = (id >> 3) * 4 + (id & 3);   // 0..255; partners id,id^4 adjacent
  const int brow = mt * 32;

  if (tid < 32) rdegS[tid] = rdeg[brow + tid];

  // ---- A staging ownership: thread -> (row sm, float4-slot sp) ----
  const int sm = tid >> 4;       // 0..31
  const int sp = tid & 15;       // 0..15 (k = sp*4..sp*4+3)
  const int kgw = sp >> 1, half = sp & 1;
  const float4* gAr = (const float4*)(inc + (size_t)(brow + sm) * NROWS) + sp;
  const float invr = invs[brow + sm];
  const int aWr = (kgw << 9) + ((sm ^ kgw) << 4) + (half << 3);

  // ---- A frag LDS offsets: frag(kh,rg): kg=kh*4+q, row=rg*16+r ----
  int aOff[2][2];
#pragma unroll
  for (int kh = 0; kh < 2; ++kh)
#pragma unroll
    for (int rg = 0; rg < 2; ++rg) {
      int kg = kh * 4 + q;
      int row = rg * 16 + r;
      aOff[kh][rg] = (kg << 9) + ((row ^ kg) << 4);
    }

  // ---- B frag ws offsets (within 32KB kt-chunk) ----
  const unsigned char* gB = bws + ((size_t)(nt * 128) << 15);
  int bOff[4];  // [kh*2+cg]
#pragma unroll
  for (int kh = 0; kh < 2; ++kh)
#pragma unroll
    for (int cg = 0; cg < 2; ++cg)
      bOff[kh * 2 + cg] = ((kh * 4 + q) << 12) + ((wv * 32 + cg * 16 + r) << 4);

  f32x4 acc[2][2];
#pragma unroll
  for (int a = 0; a < 2; ++a)
#pragma unroll
    for (int b = 0; b < 2; ++b)
      acc[a][b] = (f32x4){0.f, 0.f, 0.f, 0.f};

  float4 x, y;                   // raw A prefetch, 2 deep (static names)
  s16x8 bX[4], bY[4];            // B ping-pong

#define ISSUE_A(d, KT) do { d = gAr[(KT) * 16]; } while (0)

#define LOADB(BS, KT) do {                                                                \
    const unsigned char* _g = gB + ((size_t)(KT) << 15);                                  \
    BS[0] = *(const s16x8*)(_g + bOff[0]);                                                \
    BS[1] = *(const s16x8*)(_g + bOff[1]);                                                \
    BS[2] = *(const s16x8*)(_g + bOff[2]);                                                \
    BS[3] = *(const s16x8*)(_g + bOff[3]);                                                \
  } while (0)

// stage one float4: fused head-add (inc + mask*invs), RNE bf16, one b64 write
#define XFORM(v, BUF) do {                                                                \
    float a0 = v.x + (v.x > 0.f ? invr : 0.f);                                            \
    float a1 = v.y + (v.y > 0.f ? invr : 0.f);                                            \
    float a2 = v.z + (v.z > 0.f ? invr : 0.f);                                            \
    float a3 = v.w + (v.w > 0.f ? invr : 0.f);                                            \
    unsigned dlo, dhi;                                                                    \
    asm("v_cvt_pk_bf16_f32 %0, %1, %2" : "=v"(dlo) : "v"(a0), "v"(a1));                   \
    asm("v_cvt_pk_bf16_f32 %0, %1, %2" : "=v"(dhi) : "v"(a2), "v"(a3));                   \
    *(unsigned long long*)((BUF) + aWr) =                                                 \
        (unsigned long long)dlo | ((unsigned long long)dhi << 32);                        \
  } while (0)

#define MFMA_TILE(BUF, BS) do {                                                           \
    _Pragma("unroll")                                                                     \
    for (int kh = 0; kh < 2; ++kh) {                                                      \
      s16x8 af0 = *(const s16x8*)((BUF) + aOff[kh][0]);                                   \
      s16x8 af1 = *(const s16x8*)((BUF) + aOff[kh][1]);                                   \
      __builtin_amdgcn_s_setprio(1);                                                      \
      acc[0][0] = MFMA_(af0, BS[kh * 2 + 0], acc[0][0], 0, 0, 0);                         \
      acc[0][1] = MFMA_(af0, BS[kh * 2 + 1], acc[0][1], 0, 0, 0);                         \
      acc[1][0] = MFMA_(af1, BS[kh * 2 + 0], acc[1][0], 0, 0, 0);                         \
      acc[1][1] = MFMA_(af1, BS[kh * 2 + 1], acc[1][1], 0, 0, 0);                         \
      __builtin_amdgcn_s_setprio(0);                                                      \
    }                                                                                     \
  } while (0)

#define SYNC() do { FENCE(); WAITLGKM(); FENCE(); BARRIER(); FENCE(); } while (0)

  // ---- prologue: A-issues first (FIFO -> auto-vmcnt retires A only) ----
  ISSUE_A(x, 0);
  ISSUE_A(y, 1);
  LOADB(bX, 0);
  XFORM(x, buf0);
  XFORM(y, buf1);
  SYNC();

  // ---- steady: 31 groups x 4 tiles, ONE sync per 2 tiles ----
  for (int i = 0; i < 31; ++i) {
    const int t = i * 4;
    // half A: MFMA tiles t,t+1 (buf0,buf1); stage t+2,t+3 (buf2,buf3)
    ISSUE_A(x, t + 2);
    ISSUE_A(y, t + 3);
    LOADB(bY, t + 1);
    FENCE();
    MFMA_TILE(buf0, bX);
    XFORM(x, buf2);
    LOADB(bX, t + 2);
    FENCE();
    MFMA_TILE(buf1, bY);
    XFORM(y, buf3);
    SYNC();
    // half B: MFMA tiles t+2,t+3 (buf2,buf3); stage t+4,t+5 (buf0,buf1)
    ISSUE_A(x, t + 4);
    ISSUE_A(y, t + 5);
    LOADB(bY, t + 3);
    FENCE();
    MFMA_TILE(buf2, bX);
    XFORM(x, buf0);
    LOADB(bX, t + 4);
    FENCE();
    MFMA_TILE(buf3, bY);
    XFORM(y, buf1);
    SYNC();
  }

  // ---- tail: tiles 124..127 (entering: buf0,buf1=124,125; bX=B(124)) ----
  ISSUE_A(x, 126);
  ISSUE_A(y, 127);
  LOADB(bY, 125);
  FENCE();
  MFMA_TILE(buf0, bX);   // tile 124
  XFORM(x, buf2);        // stage 126
  LOADB(bX, 126);
  FENCE();
  MFMA_TILE(buf1, bY);   // tile 125
  XFORM(y, buf3);        // stage 127
  SYNC();
  LOADB(bY, 127);
  FENCE();
  MFMA_TILE(buf2, bX);   // tile 126
  FENCE();
  MFMA_TILE(buf3, bY);   // tile 127

  // ---- epilogue: acc * rdeg (rdegS staged at prologue, barrier'd by SYNC) ----
#pragma unroll
  for (int rg = 0; rg < 2; ++rg) {
#pragma unroll
    for (int cg = 0; cg < 2; ++cg) {
#pragma unroll
      for (int j = 0; j < 4; ++j) {
        int row = rg * 16 + q * 4 + j;
        out[(size_t)(brow + row) * DDIM + nt * 256 + wv * 32 + cg * 16 + r] =
            acc[rg][cg][j] * rdegS[row];
      }
    }
  }
#undef ISSUE_A
#undef LOADB
#undef XFORM
#undef MFMA_TILE
#undef SYNC
}

extern "C" void kernel_launch(void* const* d_in, const int* in_sizes, int n_in,
                              void* d_out, int out_size, void* d_ws, size_t ws_size,
                              hipStream_t stream) {
  const float* cur = (const float*)d_in[0];          // [8192, 512] fp32
  const float* incm = (const float*)d_in[1];         // [8192, 8192] fp32
  float* out = (float*)d_out;                        // [8192, 512] fp32
  unsigned char* ws = (unsigned char*)d_ws;
  float* invs = (float*)ws;                          // 32KB
  float* rdeg = (float*)(ws + 32768);                // 32KB
  unsigned char* bws = ws + 65536;                   // 8MB B chunks

  hipLaunchKernelGGL(stats_kernel, dim3(NROWS), dim3(256), 0, stream, incm, invs, rdeg);
  hipLaunchKernelGGL(bprep_kernel, dim3((NROWS * DDIM / 8) / 256), dim3(256), 0, stream,
                     cur, bws);
  hipLaunchKernelGGL(gemm_kernel, dim3(512), dim3(512), 0, stream, incm, bws, invs, rdeg, out);
}